// Round 4
// baseline (611.130 us; speedup 1.0000x reference)
//
#include <hip/hip_runtime.h>

typedef unsigned short u16;
typedef unsigned int u32;
typedef __attribute__((ext_vector_type(8))) __bf16 bf16x8;
typedef __attribute__((ext_vector_type(4))) float f32x4;
typedef __attribute__((ext_vector_type(16))) float f32x16;
typedef __attribute__((ext_vector_type(4))) u32 u32x4;
typedef __attribute__((ext_vector_type(2))) u32 u32x2;
typedef __attribute__((ext_vector_type(8))) u16 u16x8;

#define S_LEN 2048
#define DM 3072
#define NH 24
#define NKV 8

__device__ __forceinline__ u16 f2b(float f) {
  u32 u = __builtin_bit_cast(u32, f);
  u = u + 0x7FFFu + ((u >> 16) & 1u);
  return (u16)(u >> 16);
}
__device__ __forceinline__ float b2f(u16 h) {
  u32 u = ((u32)h) << 16;
  return __builtin_bit_cast(float, u);
}
__device__ __forceinline__ u32 cvtpk(float lo, float hi) {
  u32 r;
  asm("v_cvt_pk_bf16_f32 %0, %1, %2" : "=v"(r) : "v"(lo), "v"(hi));
  return r;
}
__device__ __forceinline__ f32x4 mfma16(bf16x8 a, bf16x8 b, f32x4 c) {
  return __builtin_amdgcn_mfma_f32_16x16x32_bf16(a, b, c, 0, 0, 0);
}
__device__ __forceinline__ f32x16 mfma32(bf16x8 a, bf16x8 b, f32x16 c) {
  return __builtin_amdgcn_mfma_f32_32x32x16_bf16(a, b, c, 0, 0, 0);
}
__device__ __forceinline__ void gload16(const u16* g, u16* l) {
  __builtin_amdgcn_global_load_lds((const __attribute__((address_space(1))) void*)g,
                                   (__attribute__((address_space(3))) void*)l, 16, 0, 0);
}

// ---------------- f32 -> bf16 conversion ----------------
__global__ __launch_bounds__(256) void cvt_kernel(const float* __restrict__ s,
                                                  u16* __restrict__ d, int n8) {
  int i = blockIdx.x * 256 + threadIdx.x;
  if (i >= n8) return;
  const f32x4* p = (const f32x4*)(s + (size_t)i * 8);
  f32x4 a = p[0], b = p[1];
  u16x8 o;
#pragma unroll
  for (int j = 0; j < 4; ++j) { o[j] = f2b(a[j]); o[j + 4] = f2b(b[j]); }
  *(u16x8*)(d + (size_t)i * 8) = o;
}

// ---------------- GEMM: C[m,n] = sum_k A[m,k] * B[n,k] ----------------
__device__ __forceinline__ void gemm_body(const u16* __restrict__ A, const u16* __restrict__ B,
                                          void* __restrict__ Cv, int N, int K,
                                          int m0, int n0, int mode) {
  __shared__ __align__(16) u16 sA[128 * 32];
  __shared__ __align__(16) u16 sB[128 * 32];
  const int tid = threadIdx.x;
  const int w = tid >> 6, lane = tid & 63;
  const int l15 = lane & 15, g = lane >> 4;
  const int wr = w >> 1, wc = w & 1;
  f32x4 acc[4][4];
#pragma unroll
  for (int i = 0; i < 4; ++i)
#pragma unroll
    for (int j = 0; j < 4; ++j) acc[i][j] = 0.f;

  for (int k0 = 0; k0 < K; k0 += 32) {
    __syncthreads();
#pragma unroll
    for (int t = 0; t < 2; ++t) {
      int jb = w * 128 + t * 64;
      int jc = jb + lane;
      int row = jc >> 2, c8 = (jc & 3) << 3;
      gload16(A + (size_t)(m0 + row) * K + k0 + c8, sA + jb * 8);
      gload16(B + (size_t)(n0 + row) * K + k0 + c8, sB + jb * 8);
    }
    __syncthreads();
    bf16x8 af[4], bfr[4];
#pragma unroll
    for (int i = 0; i < 4; ++i) {
      af[i]  = *(const bf16x8*)(sA + (wr * 64 + i * 16 + l15) * 32 + g * 8);
      bfr[i] = *(const bf16x8*)(sB + (wc * 64 + i * 16 + l15) * 32 + g * 8);
    }
#pragma unroll
    for (int i = 0; i < 4; ++i)
#pragma unroll
      for (int j = 0; j < 4; ++j)
        acc[i][j] = mfma16(af[i], bfr[j], acc[i][j]);
  }
#pragma unroll
  for (int i = 0; i < 4; ++i)
#pragma unroll
    for (int j = 0; j < 4; ++j)
#pragma unroll
      for (int r = 0; r < 4; ++r) {
        int mm = m0 + wr * 64 + i * 16 + g * 4 + r;
        int nn = n0 + wc * 64 + j * 16 + l15;
        if (mode == 1)      ((float*)Cv)[(size_t)mm * N + nn] = acc[i][j][r];
        else if (mode == 0) ((u16*)Cv)[(size_t)mm * N + nn]   = f2b(acc[i][j][r]);
        else                ((u16*)Cv)[(size_t)nn * 2048 + (size_t)(mm >> 11) * 2097152 + (mm & 2047)]
                              = f2b(acc[i][j][r]);
      }
}

__global__ __launch_bounds__(256) void gemm_bf16out(const u16* __restrict__ A, const u16* __restrict__ B,
                                                    u16* __restrict__ C, int N, int K) {
  gemm_body(A, B, C, N, K, blockIdx.y * 128, blockIdx.x * 128, 0);
}
__global__ __launch_bounds__(256) void gemm_f32out(const u16* __restrict__ A, const u16* __restrict__ B,
                                                   float* __restrict__ C, int N, int K) {
  gemm_body(A, B, C, N, K, blockIdx.y * 128, blockIdx.x * 128, 1);
}
__global__ __launch_bounds__(256) void gemm_kv(const u16* __restrict__ A,
                                               const u16* __restrict__ Bk, const u16* __restrict__ Bv,
                                               u16* __restrict__ Ck, u16* __restrict__ Cv,
                                               int N, int K) {
  bool isv = blockIdx.x >= 8;
  gemm_body(A, isv ? Bv : Bk, isv ? Cv : Ck, N, K, blockIdx.y * 128, (blockIdx.x & 7) * 128,
            isv ? 2 : 0);
}

// ---------------- RoPE (in place, bf16) — K only ----------------
__global__ __launch_bounds__(256) void rope_kernel(u16* __restrict__ t, const float* __restrict__ fc,
                                                   const float* __restrict__ fs, int nheads, int total) {
  int idx = blockIdx.x * 256 + threadIdx.x;
  if (idx >= total) return;
  int c = idx & 7;
  int tmp = idx >> 3;
  int h = tmp % nheads;
  int row = tmp / nheads;
  int s = row & (S_LEN - 1);
  int d0 = c << 3;
  u16* base = t + (size_t)row * (nheads * 128) + h * 128;
  u16x8 lo = *(const u16x8*)(base + d0);
  u16x8 hi = *(const u16x8*)(base + 64 + d0);
  const float* cp = fc + s * 64 + d0;
  const float* sp = fs + s * 64 + d0;
  u16x8 olo, ohi;
#pragma unroll
  for (int j = 0; j < 8; ++j) {
    float cv = cp[j], sn = sp[j];
    float a = b2f(lo[j]), b = b2f(hi[j]);
    olo[j] = f2b(a * cv - b * sn);
    ohi[j] = f2b(b * cv + a * sn);
  }
  *(u16x8*)(base + d0) = olo;
  *(u16x8*)(base + 64 + d0) = ohi;
}

// ---------------- causal GQA flash attention, 32x32x16 MFMA ----------------
// grid (16, H, B), block 256 = 4 waves x 32 q-rows (QBLK=128, KVBLK=64).
// Swapped QK^T: S^T[k][q], lane owns q-col = lane&31. Softmax fully in-register
// (one shfl_xor(32)); P->B-frag via v_cvt_pk_bf16_f32 + shfl_xor(32) (T12).
// K [64][128] and V^T [128][64] double-buffered via global_load_lds with
// pre-swizzled sources (chunk ^= row&7); reads apply the same XOR.
__global__ __launch_bounds__(256) void attn_kernel(const u16* __restrict__ xq,
                                                   const u16* __restrict__ xk,
                                                   const u16* __restrict__ xvT,
                                                   const float* __restrict__ fc,
                                                   const float* __restrict__ fs,
                                                   u16* __restrict__ o) {
  __shared__ __align__(16) u16 smem[32768];     // 64 KB
  const int tid = threadIdx.x;
  const int w = tid >> 6, lane = tid & 63;
  const int l31 = lane & 31, hi = lane >> 5;
  const int b = blockIdx.z, h = blockIdx.y;
  const int qb = 15 - blockIdx.x;               // long blocks first
  const int kvh = h / 3;
  const int q0 = qb * 128;
  const int qrow = q0 + w * 32 + l31;
  const float sc2 = 0.08838834764831845f * 1.4426950408889634f;  // 1/sqrt(128)*log2e

  // Q load + fused RoPE + pre-scale; qf[dc] = Q[q][dc*16 + hi*8 + j]
  bf16x8 qf[8];
  {
    const u16* qptr = xq + (size_t)(b * S_LEN + qrow) * DM + h * 128 + hi * 8;
    u16x8 raw[8];
#pragma unroll
    for (int dc = 0; dc < 8; ++dc) raw[dc] = *(const u16x8*)(qptr + dc * 16);
#pragma unroll
    for (int dcp = 0; dcp < 4; ++dcp) {
      const float* cp = fc + qrow * 64 + dcp * 16 + hi * 8;
      const float* sp = fs + qrow * 64 + dcp * 16 + hi * 8;
      f32x4 c0 = *(const f32x4*)cp, c1 = *(const f32x4*)(cp + 4);
      f32x4 s0 = *(const f32x4*)sp, s1 = *(const f32x4*)(sp + 4);
      bf16x8 qlo, qhi;
#pragma unroll
      for (int j = 0; j < 8; ++j) {
        float cv = j < 4 ? c0[j & 3] : c1[j & 3];
        float sn = j < 4 ? s0[j & 3] : s1[j & 3];
        float a = b2f(raw[dcp][j]), bb = b2f(raw[dcp + 4][j]);
        qlo[j] = (__bf16)((a * cv - bb * sn) * sc2);
        qhi[j] = (__bf16)((bb * cv + a * sn) * sc2);
      }
      qf[dcp] = qlo;
      qf[dcp + 4] = qhi;
    }
  }

  // staging: LDS linear chunk j of row r holds global chunk j^(r&7) (low 3 bits)
  const u16* ksrc = xk + (size_t)b * 2097152 + kvh * 128;          // [s][1024]
  const u16* vsrc = xvT + (size_t)(b * 1024 + kvh * 128) * 2048;   // [d][2048]
  int koff[4], vofs[4], dst4[4];
#pragma unroll
  for (int r = 0; r < 4; ++r) {
    int ck = r * 256 + tid;                    // K: 64 rows x 16 chunks
    int krow = ck >> 4, kj = (ck & 15) ^ (krow & 7);
    koff[r] = krow * 1024 + kj * 8;
    int cv = r * 256 + tid;                    // V^T: 128 rows x 8 chunks
    int vrow = cv >> 3, vj = (cv & 7) ^ (vrow & 7);
    vofs[r] = vrow * 2048 + vj * 8;
    dst4[r] = (r * 256 + (tid & 192)) * 8;     // wave-uniform LDS chunk base
  }

  u16 *sKc = smem, *sKn = smem + 8192;
  u16 *sVc = smem + 16384, *sVn = smem + 24576;

  f32x16 accO[4];
#pragma unroll
  for (int i = 0; i < 4; ++i)
#pragma unroll
    for (int e = 0; e < 16; ++e) accO[i][e] = 0.f;
  float m = -1e30f, lsum = 0.f;
  const int nt = 2 * qb + 2;

#pragma unroll
  for (int r = 0; r < 4; ++r) gload16(ksrc + koff[r], sKc + dst4[r]);
#pragma unroll
  for (int r = 0; r < 4; ++r) gload16(vsrc + vofs[r], sVc + dst4[r]);
  __syncthreads();

  for (int t = 0; t < nt; ++t) {
    if (t + 1 < nt) {
      int k0n = (t + 1) * 64;
#pragma unroll
      for (int r = 0; r < 4; ++r) gload16(ksrc + (size_t)k0n * 1024 + koff[r], sKn + dst4[r]);
#pragma unroll
      for (int r = 0; r < 4; ++r) gload16(vsrc + k0n + vofs[r], sVn + dst4[r]);
    }
    if (64 * t <= q0 + w * 32 + 31) {           // wave-level causal skip
      // QK^T: S^T[k][q] = sum_d K[k][d] Q[q][d]
      f32x16 st[2];
#pragma unroll
      for (int s = 0; s < 2; ++s)
#pragma unroll
        for (int e = 0; e < 16; ++e) st[s][e] = 0.f;
      __builtin_amdgcn_s_setprio(1);
#pragma unroll
      for (int s = 0; s < 2; ++s) {
        int r = s * 32 + l31, r8 = r & 7;
#pragma unroll
        for (int dsub = 0; dsub < 8; ++dsub) {
          int j = (dsub * 2 + hi) ^ r8;
          bf16x8 kf = *(const bf16x8*)(sKc + r * 128 + j * 8);
          st[s] = mfma32(kf, qf[dsub], st[s]);
        }
      }
      __builtin_amdgcn_s_setprio(0);
      // mask + online softmax (k-row of reg r: (r&3)+8*(r>>2)+4*hi)
      float p[2][16];
      float pmax = -1e30f;
#pragma unroll
      for (int s = 0; s < 2; ++s)
#pragma unroll
        for (int r = 0; r < 16; ++r) {
          float x = st[s][r];
          if (t >= nt - 2) {
            int kk = t * 64 + s * 32 + (r & 3) + 8 * (r >> 2) + 4 * hi;
            if (kk > qrow) x = -1e30f;
          }
          p[s][r] = x;
          pmax = fmaxf(pmax, x);
        }
      pmax = fmaxf(pmax, __shfl_xor(pmax, 32));
      if (!__all(pmax - m <= 8.0f)) {
        float mnew = fmaxf(m, pmax);
        float corr = exp2f(m - mnew);
        lsum *= corr;
#pragma unroll
        for (int i = 0; i < 4; ++i)
#pragma unroll
          for (int e = 0; e < 16; ++e) accO[i][e] *= corr;
        m = mnew;
      }
      float ps = 0.f;
#pragma unroll
      for (int s = 0; s < 2; ++s)
#pragma unroll
        for (int r = 0; r < 16; ++r) {
          float e2 = exp2f(p[s][r] - m);
          p[s][r] = e2;
          ps += e2;
        }
      ps += __shfl_xor(ps, 32);
      lsum += ps;
      // P -> B fragments (T12): per k-slice kap, B row kk = hB*8+j, q = l31.
      // source reg r = 4*(2*(kap&1)+hB)+(j&3), source half = j>>2.
      bf16x8 pB[4];
#pragma unroll
      for (int kap = 0; kap < 4; ++kap) {
        int s = kap >> 1, base = 8 * (kap & 1);
        u32 wA0 = cvtpk(p[s][base + 0], p[s][base + 1]);
        u32 wA1 = cvtpk(p[s][base + 2], p[s][base + 3]);
        u32 wB0 = cvtpk(p[s][base + 4], p[s][base + 5]);
        u32 wB1 = cvtpk(p[s][base + 6], p[s][base + 7]);
        u32 own0 = hi ? wB0 : wA0, own1 = hi ? wB1 : wA1;   // our regs for consumers hB = our hi
        u32 oth0 = hi ? wA0 : wB0, oth1 = hi ? wA1 : wB1;   // what our partner consumer needs
        u32 pw0 = __shfl_xor(oth0, 32);
        u32 pw1 = __shfl_xor(oth1, 32);
        u32x4 fr;
        fr[0] = hi ? pw0 : own0;
        fr[1] = hi ? pw1 : own1;
        fr[2] = hi ? own0 : pw0;
        fr[3] = hi ? own1 : pw1;
        pB[kap] = __builtin_bit_cast(bf16x8, fr);
      }
      // PV: O^T[d][q] += V^T[d][k] * P[k][q]
      __builtin_amdgcn_s_setprio(1);
#pragma unroll
      for (int dsub = 0; dsub < 4; ++dsub) {
        int rv = dsub * 32 + l31, rv8 = rv & 7;
#pragma unroll
        for (int kap = 0; kap < 4; ++kap) {
          int j = (kap * 2 + hi) ^ rv8;
          bf16x8 vf = *(const bf16x8*)(sVc + rv * 64 + j * 8);
          accO[dsub] = mfma32(vf, pB[kap], accO[dsub]);
        }
      }
      __builtin_amdgcn_s_setprio(0);
    }
    __syncthreads();                            // drains stage vmcnt + cur reads done
    u16* tk = sKc; sKc = sKn; sKn = tk;
    u16* tv = sVc; sVc = sVn; sVn = tv;
  }
  // epilogue: normalize, pack, LDS transpose (chunk-XOR), coalesced writes
  u16* sO = smem + w * 4096;                    // per-wave [32 q][128 d]
  float invl = 1.0f / lsum;
#pragma unroll
  for (int dsub = 0; dsub < 4; ++dsub)
#pragma unroll
    for (int gq = 0; gq < 4; ++gq) {
      u32 w0 = cvtpk(accO[dsub][gq * 4 + 0] * invl, accO[dsub][gq * 4 + 1] * invl);
      u32 w1 = cvtpk(accO[dsub][gq * 4 + 2] * invl, accO[dsub][gq * 4 + 3] * invl);
      int chunk = (dsub * 4 + gq) ^ l31;        // 16 chunks, XOR q&15 (l31&15)
      u32x2 pr; pr[0] = w0; pr[1] = w1;
      *(u32x2*)(sO + l31 * 128 + (chunk & 15) * 8 + 4 * hi) = pr;
    }
  __syncthreads();
#pragma unroll
  for (int p2 = 0; p2 < 8; ++p2) {
    int idx = p2 * 64 + lane;
    int q = idx >> 4, c = idx & 15;
    int j = c ^ (q & 15);
    u32x4 v = *(const u32x4*)(sO + q * 128 + j * 8);
    *(u32x4*)(o + (size_t)(b * S_LEN + q0 + w * 32 + q) * DM + h * 128 + c * 8) = v;
  }
}

// ---------------- launch ----------------
extern "C" void kernel_launch(void* const* d_in, const int* in_sizes, int n_in,
                              void* d_out, int out_size, void* d_ws, size_t ws_size,
                              hipStream_t stream) {
  const float* x  = (const float*)d_in[0];
  const float* fc = (const float*)d_in[1];
  const float* fs = (const float*)d_in[2];
  const float* wq = (const float*)d_in[4];
  const float* wk = (const float*)d_in[5];
  const float* wv = (const float*)d_in[6];
  const float* wo = (const float*)d_in[7];
  float* out = (float*)d_out;
  char* ws = (char*)d_ws;

  u16* xb  = (u16*)(ws);                 // x bf16      25,165,824
  u16* wqb = (u16*)(ws + 25165824);      // wq bf16     18,874,368
  u16* att = (u16*)(ws + 25165824);      // attn out (aliases wq/wk after death)
  u16* wkb = (u16*)(ws + 44040192);      // wk bf16      6,291,456
  u16* wvb = (u16*)(ws + 50331648);      // wv bf16      6,291,456
  u16* xqb = (u16*)(ws + 56623104);      // xq bf16     25,165,824
  u16* xkb = (u16*)(ws + 81788928);      // xk bf16      8,388,608
  u16* xvT = (u16*)(ws + 90177536);      // V^T bf16     8,388,608
  u16* wob = (u16*)(ws);                 // wo bf16 (aliases xb after death)

  cvt_kernel<<<6144, 256, 0, stream>>>(x,  xb,  1572864);
  cvt_kernel<<<4608, 256, 0, stream>>>(wq, wqb, 1179648);
  cvt_kernel<<<1536, 256, 0, stream>>>(wk, wkb,  393216);
  cvt_kernel<<<1536, 256, 0, stream>>>(wv, wvb,  393216);

  gemm_bf16out<<<dim3(24, 32), 256, 0, stream>>>(xb, wqb, xqb, 3072, 3072);
  gemm_kv<<<dim3(16, 32), 256, 0, stream>>>(xb, wkb, wvb, xkb, xvT, 1024, 3072);

  rope_kernel<<<1024, 256, 0, stream>>>(xkb, fc, fs, NKV, 4096 * NKV * 8);  // K only

  attn_kernel<<<dim3(16, NH, 2), 256, 0, stream>>>(xqb, xkb, xvT, fc, fs, att);

  cvt_kernel<<<4608, 256, 0, stream>>>(wo, wob, 1179648);
  gemm_f32out<<<dim3(24, 32), 256, 0, stream>>>(att, wob, out, 3072, 3072);
}

// Round 5
// 512.987 us; speedup vs baseline: 1.1913x; 1.1913x over previous
//
#include <hip/hip_runtime.h>

typedef unsigned short u16;
typedef unsigned int u32;
typedef __attribute__((ext_vector_type(8))) __bf16 bf16x8;
typedef __attribute__((ext_vector_type(4))) float f32x4;
typedef __attribute__((ext_vector_type(4))) u32 u32x4;
typedef __attribute__((ext_vector_type(8))) u16 u16x8;

#define S_LEN 2048
#define DM 3072
#define NH 24
#define NKV 8

__device__ __forceinline__ u16 f2b(float f) {
  u32 u = __builtin_bit_cast(u32, f);
  u = u + 0x7FFFu + ((u >> 16) & 1u);
  return (u16)(u >> 16);
}
__device__ __forceinline__ float b2f(u16 h) {
  u32 u = ((u32)h) << 16;
  return __builtin_bit_cast(float, u);
}
__device__ __forceinline__ u32 cvtpk(float lo, float hi) {
  u32 r;
  asm("v_cvt_pk_bf16_f32 %0, %1, %2" : "=v"(r) : "v"(lo), "v"(hi));
  return r;
}
__device__ __forceinline__ f32x4 mfma16(bf16x8 a, bf16x8 b, f32x4 c) {
  return __builtin_amdgcn_mfma_f32_16x16x32_bf16(a, b, c, 0, 0, 0);
}
__device__ __forceinline__ void gload16(const u16* g, u16* l) {
  __builtin_amdgcn_global_load_lds((const __attribute__((address_space(1))) void*)g,
                                   (__attribute__((address_space(3))) void*)l, 16, 0, 0);
}

// ---------------- f32 -> bf16 conversion ----------------
__device__ __forceinline__ void cvt_one(const float* __restrict__ s, u16* __restrict__ d, int j) {
  const f32x4* p = (const f32x4*)(s + (size_t)j * 8);
  f32x4 a = p[0], b = p[1];
  u16x8 o;
#pragma unroll
  for (int q = 0; q < 4; ++q) { o[q] = f2b(a[q]); o[q + 4] = f2b(b[q]); }
  *(u16x8*)(d + (size_t)j * 8) = o;
}
__global__ __launch_bounds__(256) void cvt_kernel(const float* __restrict__ s,
                                                  u16* __restrict__ d, int n8) {
  int i = blockIdx.x * 256 + threadIdx.x;
  if (i >= n8) return;
  cvt_one(s, d, i);
}
// x (1572864), wq (1179648), wk (393216), wv (393216) in one dispatch; all
// segment boundaries are multiples of 256 so branches are block-uniform.
__global__ __launch_bounds__(256) void cvt4_kernel(const float* __restrict__ s0, u16* __restrict__ d0,
                                                   const float* __restrict__ s1, u16* __restrict__ d1,
                                                   const float* __restrict__ s2, u16* __restrict__ d2,
                                                   const float* __restrict__ s3, u16* __restrict__ d3) {
  int i = blockIdx.x * 256 + threadIdx.x;
  if (i < 1572864)      cvt_one(s0, d0, i);
  else if (i < 2752512) cvt_one(s1, d1, i - 1572864);
  else if (i < 3145728) cvt_one(s2, d2, i - 2752512);
  else                  cvt_one(s3, d3, i - 3145728);
}

// ---------------- GEMM: C[m,n] = sum_k A[m,k] * B[n,k] ----------------
// 128x128 tile, BK=32, 4 waves, m97 structure. XCD-aware block swizzle.
__device__ __forceinline__ void swz_bid(int& bx, int& by) {
  int gx = gridDim.x;
  int tot = gx * gridDim.y;          // must be divisible by 8
  int id = blockIdx.y * gx + blockIdx.x;
  int cpx = tot >> 3;
  int s = (id & 7) * cpx + (id >> 3);
  bx = s % gx;
  by = s / gx;
}
__device__ __forceinline__ void gemm_body(const u16* __restrict__ A, const u16* __restrict__ B,
                                          void* __restrict__ Cv, int N, int K,
                                          int m0, int n0, int mode) {
  __shared__ __align__(16) u16 sA[128 * 32];
  __shared__ __align__(16) u16 sB[128 * 32];
  const int tid = threadIdx.x;
  const int w = tid >> 6, lane = tid & 63;
  const int l15 = lane & 15, g = lane >> 4;
  const int wr = w >> 1, wc = w & 1;
  f32x4 acc[4][4];
#pragma unroll
  for (int i = 0; i < 4; ++i)
#pragma unroll
    for (int j = 0; j < 4; ++j) acc[i][j] = 0.f;

  for (int k0 = 0; k0 < K; k0 += 32) {
    __syncthreads();
#pragma unroll
    for (int t = 0; t < 2; ++t) {
      int jb = w * 128 + t * 64;
      int jc = jb + lane;
      int row = jc >> 2, c8 = (jc & 3) << 3;
      gload16(A + (size_t)(m0 + row) * K + k0 + c8, sA + jb * 8);
      gload16(B + (size_t)(n0 + row) * K + k0 + c8, sB + jb * 8);
    }
    __syncthreads();
    bf16x8 af[4], bfr[4];
#pragma unroll
    for (int i = 0; i < 4; ++i) {
      af[i]  = *(const bf16x8*)(sA + (wr * 64 + i * 16 + l15) * 32 + g * 8);
      bfr[i] = *(const bf16x8*)(sB + (wc * 64 + i * 16 + l15) * 32 + g * 8);
    }
#pragma unroll
    for (int i = 0; i < 4; ++i)
#pragma unroll
      for (int j = 0; j < 4; ++j)
        acc[i][j] = mfma16(af[i], bfr[j], acc[i][j]);
  }
#pragma unroll
  for (int i = 0; i < 4; ++i)
#pragma unroll
    for (int j = 0; j < 4; ++j)
#pragma unroll
      for (int r = 0; r < 4; ++r) {
        int mm = m0 + wr * 64 + i * 16 + g * 4 + r;
        int nn = n0 + wc * 64 + j * 16 + l15;
        if (mode == 1)      ((float*)Cv)[(size_t)mm * N + nn] = acc[i][j][r];
        else if (mode == 0) ((u16*)Cv)[(size_t)mm * N + nn]   = f2b(acc[i][j][r]);
        else                ((u16*)Cv)[(size_t)nn * 2048 + (size_t)(mm >> 11) * 2097152 + (mm & 2047)]
                              = f2b(acc[i][j][r]);
      }
}

__global__ __launch_bounds__(256) void gemm_bf16out(const u16* __restrict__ A, const u16* __restrict__ B,
                                                    u16* __restrict__ C, int N, int K) {
  int bx, by; swz_bid(bx, by);
  gemm_body(A, B, C, N, K, by * 128, bx * 128, 0);
}
__global__ __launch_bounds__(256) void gemm_f32out(const u16* __restrict__ A, const u16* __restrict__ B,
                                                   float* __restrict__ C, int N, int K) {
  int bx, by; swz_bid(bx, by);
  gemm_body(A, B, C, N, K, by * 128, bx * 128, 1);
}
__global__ __launch_bounds__(256) void gemm_kv(const u16* __restrict__ A,
                                               const u16* __restrict__ Bk, const u16* __restrict__ Bv,
                                               u16* __restrict__ Ck, u16* __restrict__ Cv,
                                               int N, int K) {
  int bx, by; swz_bid(bx, by);
  bool isv = bx >= 8;
  gemm_body(A, isv ? Bv : Bk, isv ? Cv : Ck, N, K, by * 128, (bx & 7) * 128, isv ? 2 : 0);
}

// ---------------- RoPE (in place, bf16) — K only ----------------
__global__ __launch_bounds__(256) void rope_kernel(u16* __restrict__ t, const float* __restrict__ fc,
                                                   const float* __restrict__ fs, int nheads, int total) {
  int idx = blockIdx.x * 256 + threadIdx.x;
  if (idx >= total) return;
  int c = idx & 7;
  int tmp = idx >> 3;
  int h = tmp % nheads;
  int row = tmp / nheads;
  int s = row & (S_LEN - 1);
  int d0 = c << 3;
  u16* base = t + (size_t)row * (nheads * 128) + h * 128;
  u16x8 lo = *(const u16x8*)(base + d0);
  u16x8 hi = *(const u16x8*)(base + 64 + d0);
  const float* cp = fc + s * 64 + d0;
  const float* sp = fs + s * 64 + d0;
  u16x8 olo, ohi;
#pragma unroll
  for (int j = 0; j < 8; ++j) {
    float cv = cp[j], sn = sp[j];
    float a = b2f(lo[j]), b = b2f(hi[j]);
    olo[j] = f2b(a * cv - b * sn);
    ohi[j] = f2b(b * cv + a * sn);
  }
  *(u16x8*)(base + d0) = olo;
  *(u16x8*)(base + 64 + d0) = ohi;
}

// ---------------- causal GQA flash attention ----------------
// grid: (S/128, H, B); block 512 (8 waves x 16 q-rows). Swapped QK^T (lane owns
// q-row = lane&15), exp2-domain softmax, Q-RoPE fused. K and V^T double-buffered
// via global_load_lds w/ pre-swizzled sources. P stays in registers: cvt_pk to
// bf16 then cross-g-group __shfl redistribution (no P LDS). 64 KB LDS -> 2
// blocks/CU (16 waves).
__global__ __launch_bounds__(512) void attn_kernel(const u16* __restrict__ xq,
                                                   const u16* __restrict__ xk,
                                                   const u16* __restrict__ xvT,
                                                   const float* __restrict__ fc,
                                                   const float* __restrict__ fs,
                                                   u16* __restrict__ o) {
  __shared__ __align__(16) u16 smem[32768];     // 64 KB: K dbuf 32K + V^T dbuf 32K
  const int tid = threadIdx.x;
  const int w = tid >> 6, lane = tid & 63;
  const int l15 = lane & 15, g = lane >> 4;
  const int b = blockIdx.z, h = blockIdx.y;
  const int qb = 15 - blockIdx.x;               // long blocks first
  const int kvh = h / 3;
  const int q0 = qb * 128;
  const int qrow = q0 + w * 16 + l15;
  const u16* qptr = xq + (size_t)(b * S_LEN + qrow) * DM + h * 128;
  const float sc2 = 0.08838834764831845f * 1.4426950408889634f;  // 1/sqrt(128)*log2e

  // Q load + fused RoPE + pre-scale
  bf16x8 qf[4];
#pragma unroll
  for (int dcp = 0; dcp < 2; ++dcp) {
    u16x8 Lo = *(const u16x8*)(qptr + dcp * 32 + g * 8);
    u16x8 Hi = *(const u16x8*)(qptr + 64 + dcp * 32 + g * 8);
    const float* cp = fc + qrow * 64 + dcp * 32 + g * 8;
    const float* sp = fs + qrow * 64 + dcp * 32 + g * 8;
    bf16x8 qlo, qhi;
#pragma unroll
    for (int j = 0; j < 8; ++j) {
      float cv = cp[j], sn = sp[j];
      float a = b2f(Lo[j]), bb = b2f(Hi[j]);
      qlo[j] = (__bf16)((a * cv - bb * sn) * sc2);
      qhi[j] = (__bf16)((bb * cv + a * sn) * sc2);
    }
    qf[dcp] = qlo;
    qf[dcp + 2] = qhi;
  }

  // staging addresses: dest linear chunk c holds global chunk c^(row&7) of its row
  const u16* ksrc = xk + (size_t)b * 2097152 + kvh * 128;          // [s][1024]
  const u16* vsrc = xvT + (size_t)(b * 1024 + kvh * 128) * 2048;   // [d][2048]
  int koff[2], vofs[2], dst[2];
#pragma unroll
  for (int r = 0; r < 2; ++r) {
    int ck = r * 512 + tid;                    // K tile: 64 rows x 16 chunks
    int krow = ck >> 4, kj = (ck & 15) ^ (krow & 7);
    koff[r] = krow * 1024 + kj * 8;
    int cv = r * 512 + tid;                    // V^T tile: 128 rows x 8 chunks
    int vrow = cv >> 3, vj = (cv & 7) ^ (vrow & 7);
    vofs[r] = vrow * 2048 + vj * 8;
    dst[r] = (r * 512 + (tid & 448)) * 8;      // wave-uniform LDS chunk base
  }

  u16 *sKc = smem, *sKn = smem + 8192;
  u16 *sVc = smem + 16384, *sVn = smem + 24576;

  f32x4 accO[8];
#pragma unroll
  for (int i = 0; i < 8; ++i) accO[i] = 0.f;
  float m = -1e30f, lsum = 0.f;
  const int nt = 2 * qb + 2;

#pragma unroll
  for (int r = 0; r < 2; ++r) gload16(ksrc + koff[r], sKc + dst[r]);
#pragma unroll
  for (int r = 0; r < 2; ++r) gload16(vsrc + vofs[r], sVc + dst[r]);
  __syncthreads();

  for (int t = 0; t < nt; ++t) {
    if (t + 1 < nt) {
      int k0n = (t + 1) * 64;
#pragma unroll
      for (int r = 0; r < 2; ++r) gload16(ksrc + (size_t)k0n * 1024 + koff[r], sKn + dst[r]);
#pragma unroll
      for (int r = 0; r < 2; ++r) gload16(vsrc + k0n + vofs[r], sVn + dst[r]);
    }
    if (64 * t <= q0 + w * 16 + 15) {           // wave-level causal skip
      // S^T[k][q] = sum_d K[k][d] Q[q][d]
      f32x4 st[4];
      __builtin_amdgcn_s_setprio(1);
#pragma unroll
      for (int kt = 0; kt < 4; ++kt) {
        f32x4 a = 0.f;
        int row = kt * 16 + l15;
#pragma unroll
        for (int dc = 0; dc < 4; ++dc) {
          bf16x8 kf = *(const bf16x8*)(sKc + row * 128 + ((dc * 32 + g * 8) ^ ((row & 7) << 3)));
          a = mfma16(kf, qf[dc], a);
        }
        st[kt] = a;
      }
      __builtin_amdgcn_s_setprio(0);
      // causal mask (last two tiles only) + online softmax
      float sv[4][4];
      float pmax = -1e30f;
#pragma unroll
      for (int kt = 0; kt < 4; ++kt)
#pragma unroll
        for (int r = 0; r < 4; ++r) {
          float x = st[kt][r];
          if (t >= nt - 2) {
            int kk = t * 64 + kt * 16 + g * 4 + r;
            if (kk > qrow) x = -1e30f;
          }
          sv[kt][r] = x;
          pmax = fmaxf(pmax, x);
        }
      pmax = fmaxf(pmax, __shfl_xor(pmax, 16));
      pmax = fmaxf(pmax, __shfl_xor(pmax, 32));
      if (!__all(pmax - m <= 8.0f)) {          // defer-max
        float mnew = fmaxf(m, pmax);
        float corr = exp2f(m - mnew);
        lsum *= corr;
#pragma unroll
        for (int i = 0; i < 8; ++i) accO[i] *= corr;
        m = mnew;
      }
      // exp2 + pack P to bf16 pairs (register-resident, no LDS)
      float ps = 0.f;
      u32 pk2[4][2];
#pragma unroll
      for (int kt = 0; kt < 4; ++kt) {
        float e0 = exp2f(sv[kt][0] - m);
        float e1 = exp2f(sv[kt][1] - m);
        float e2 = exp2f(sv[kt][2] - m);
        float e3 = exp2f(sv[kt][3] - m);
        ps += (e0 + e1) + (e2 + e3);
        pk2[kt][0] = cvtpk(e0, e1);
        pk2[kt][1] = cvtpk(e2, e3);
      }
      ps += __shfl_xor(ps, 16);
      ps += __shfl_xor(ps, 32);
      lsum += ps;
      // P redistribution: consumer (g,l15) frag ck needs P[k=ck*32+g*8+j][q=l15]
      // = pk2[2ck+(g>>1)] from lanes 32*(g&1)+l15 (j<4) and +16 (j>=4).
      bf16x8 pf[2];
      const int srcA = ((g & 1) << 5) + l15;
      const bool h2 = (g >> 1) != 0;
#pragma unroll
      for (int ck = 0; ck < 2; ++ck) {
        u32 a0 = __shfl(pk2[2 * ck][0], srcA, 64);
        u32 a1 = __shfl(pk2[2 * ck][1], srcA, 64);
        u32 a2 = __shfl(pk2[2 * ck][0], srcA + 16, 64);
        u32 a3 = __shfl(pk2[2 * ck][1], srcA + 16, 64);
        u32 b0 = __shfl(pk2[2 * ck + 1][0], srcA, 64);
        u32 b1 = __shfl(pk2[2 * ck + 1][1], srcA, 64);
        u32 b2 = __shfl(pk2[2 * ck + 1][0], srcA + 16, 64);
        u32 b3 = __shfl(pk2[2 * ck + 1][1], srcA + 16, 64);
        u32x4 fr;
        fr[0] = h2 ? b0 : a0;
        fr[1] = h2 ? b1 : a1;
        fr[2] = h2 ? b2 : a2;
        fr[3] = h2 ? b3 : a3;
        pf[ck] = __builtin_bit_cast(bf16x8, fr);
      }
      // PV: O^T[d][q] += V^T[d][k] * P[k][q]
      __builtin_amdgcn_s_setprio(1);
#pragma unroll
      for (int dt = 0; dt < 8; ++dt) {
        int row = dt * 16 + l15;
#pragma unroll
        for (int ck = 0; ck < 2; ++ck) {
          bf16x8 vf = *(const bf16x8*)(sVc + row * 64 + ((ck * 32 + g * 8) ^ ((row & 7) << 3)));
          accO[dt] = mfma16(vf, pf[ck], accO[dt]);
        }
      }
      __builtin_amdgcn_s_setprio(0);
    }
    __syncthreads();                            // drains stage vmcnt + cur reads done
    u16* tk = sKc; sKc = sKn; sKn = tk;
    u16* tv = sVc; sVc = sVn; sVn = tv;
  }
  // epilogue: normalize, transpose via LDS (wave-local region), coalesced writes
  u16* sO = smem + w * 2048;                    // per-wave [16][128], XOR-swizzled
  float invl = 1.0f / lsum;
#pragma unroll
  for (int dt = 0; dt < 8; ++dt)
#pragma unroll
    for (int r = 0; r < 4; ++r) {
      int d = dt * 16 + g * 4 + r;
      sO[(l15 * 128 + d) ^ ((l15 & 7) << 3)] = f2b(accO[dt][r] * invl);
    }
#pragma unroll
  for (int p = 0; p < 4; ++p) {
    int idx = p * 64 + lane;
    int q = idx >> 4, d0 = (idx & 15) << 3;
    u32x4 v = *(const u32x4*)(sO + ((q * 128 + d0) ^ ((q & 7) << 3)));
    *(u32x4*)(o + (size_t)(b * S_LEN + q0 + w * 16 + q) * DM + h * 128 + d0) = v;
  }
}

// ---------------- launch ----------------
extern "C" void kernel_launch(void* const* d_in, const int* in_sizes, int n_in,
                              void* d_out, int out_size, void* d_ws, size_t ws_size,
                              hipStream_t stream) {
  const float* x  = (const float*)d_in[0];
  const float* fc = (const float*)d_in[1];
  const float* fs = (const float*)d_in[2];
  const float* wq = (const float*)d_in[4];
  const float* wk = (const float*)d_in[5];
  const float* wv = (const float*)d_in[6];
  const float* wo = (const float*)d_in[7];
  float* out = (float*)d_out;
  char* ws = (char*)d_ws;

  u16* xb  = (u16*)(ws);                 // x bf16      25,165,824
  u16* wqb = (u16*)(ws + 25165824);      // wq bf16     18,874,368
  u16* att = (u16*)(ws + 25165824);      // attn out (aliases wq/wk after death)
  u16* wkb = (u16*)(ws + 44040192);      // wk bf16      6,291,456
  u16* wvb = (u16*)(ws + 50331648);      // wv bf16      6,291,456
  u16* xqb = (u16*)(ws + 56623104);      // xq bf16     25,165,824
  u16* xkb = (u16*)(ws + 81788928);      // xk bf16      8,388,608
  u16* xvT = (u16*)(ws + 90177536);      // V^T bf16     8,388,608
  u16* wob = (u16*)(ws);                 // wo bf16 (aliases xb after death)

  cvt4_kernel<<<13824, 256, 0, stream>>>(x, xb, wq, wqb, wk, wkb, wv, wvb);

  gemm_bf16out<<<dim3(24, 32), 256, 0, stream>>>(xb, wqb, xqb, 3072, 3072);
  gemm_kv<<<dim3(16, 32), 256, 0, stream>>>(xb, wkb, wvb, xkb, xvT, 1024, 3072);

  cvt_kernel<<<4608, 256, 0, stream>>>(wo, wob, 1179648);   // after gemm_kv (aliases xb)
  rope_kernel<<<1024, 256, 0, stream>>>(xkb, fc, fs, NKV, 4096 * NKV * 8);  // K only

  attn_kernel<<<dim3(16, NH, 2), 512, 0, stream>>>(xqb, xkb, xvT, fc, fs, att);

  gemm_f32out<<<dim3(24, 32), 256, 0, stream>>>(att, wob, out, 3072, 3072);
}

// Round 6
// 499.015 us; speedup vs baseline: 1.2247x; 1.0280x over previous
//
#include <hip/hip_runtime.h>

typedef unsigned short u16;
typedef unsigned int u32;
typedef __attribute__((ext_vector_type(8))) __bf16 bf16x8;
typedef __attribute__((ext_vector_type(4))) float f32x4;
typedef __attribute__((ext_vector_type(4))) u32 u32x4;
typedef __attribute__((ext_vector_type(8))) u16 u16x8;

#define S_LEN 2048
#define DM 3072
#define NH 24
#define NKV 8

__device__ __forceinline__ u16 f2b(float f) {
  u32 u = __builtin_bit_cast(u32, f);
  u = u + 0x7FFFu + ((u >> 16) & 1u);
  return (u16)(u >> 16);
}
__device__ __forceinline__ float b2f(u16 h) {
  u32 u = ((u32)h) << 16;
  return __builtin_bit_cast(float, u);
}
__device__ __forceinline__ u32 cvtpk(float lo, float hi) {
  u32 r;
  asm("v_cvt_pk_bf16_f32 %0, %1, %2" : "=v"(r) : "v"(lo), "v"(hi));
  return r;
}
__device__ __forceinline__ f32x4 mfma16(bf16x8 a, bf16x8 b, f32x4 c) {
  return __builtin_amdgcn_mfma_f32_16x16x32_bf16(a, b, c, 0, 0, 0);
}
__device__ __forceinline__ void gload16(const u16* g, u16* l) {
  __builtin_amdgcn_global_load_lds((const __attribute__((address_space(1))) void*)g,
                                   (__attribute__((address_space(3))) void*)l, 16, 0, 0);
}

// ---------------- f32 -> bf16 conversion ----------------
__device__ __forceinline__ void cvt_one(const float* __restrict__ s, u16* __restrict__ d, int j) {
  const f32x4* p = (const f32x4*)(s + (size_t)j * 8);
  f32x4 a = p[0], b = p[1];
  u16x8 o;
#pragma unroll
  for (int q = 0; q < 4; ++q) { o[q] = f2b(a[q]); o[q + 4] = f2b(b[q]); }
  *(u16x8*)(d + (size_t)j * 8) = o;
}
__global__ __launch_bounds__(256) void cvt_kernel(const float* __restrict__ s,
                                                  u16* __restrict__ d, int n8) {
  int i = blockIdx.x * 256 + threadIdx.x;
  if (i >= n8) return;
  cvt_one(s, d, i);
}
__global__ __launch_bounds__(256) void cvt4_kernel(const float* __restrict__ s0, u16* __restrict__ d0,
                                                   const float* __restrict__ s1, u16* __restrict__ d1,
                                                   const float* __restrict__ s2, u16* __restrict__ d2,
                                                   const float* __restrict__ s3, u16* __restrict__ d3) {
  int i = blockIdx.x * 256 + threadIdx.x;
  if (i < 1572864)      cvt_one(s0, d0, i);
  else if (i < 2752512) cvt_one(s1, d1, i - 1572864);
  else if (i < 3145728) cvt_one(s2, d2, i - 2752512);
  else                  cvt_one(s3, d3, i - 3145728);
}

// ---------------- GEMM: C[m,n] = sum_k A[m,k] * B[n,k] ----------------
// 128x128 tile, BK=32, 4 waves, m97 structure. XCD-aware block swizzle.
__device__ __forceinline__ void swz_bid(int& bx, int& by) {
  int gx = gridDim.x;
  int tot = gx * gridDim.y;          // must be divisible by 8
  int id = blockIdx.y * gx + blockIdx.x;
  int cpx = tot >> 3;
  int s = (id & 7) * cpx + (id >> 3);
  bx = s % gx;
  by = s / gx;
}
__device__ __forceinline__ void gemm_body(const u16* __restrict__ A, const u16* __restrict__ B,
                                          void* __restrict__ Cv, int N, int K,
                                          int m0, int n0, int mode) {
  __shared__ __align__(16) u16 sA[128 * 32];
  __shared__ __align__(16) u16 sB[128 * 32];
  const int tid = threadIdx.x;
  const int w = tid >> 6, lane = tid & 63;
  const int l15 = lane & 15, g = lane >> 4;
  const int wr = w >> 1, wc = w & 1;
  f32x4 acc[4][4];
#pragma unroll
  for (int i = 0; i < 4; ++i)
#pragma unroll
    for (int j = 0; j < 4; ++j) acc[i][j] = 0.f;

  for (int k0 = 0; k0 < K; k0 += 32) {
    __syncthreads();
#pragma unroll
    for (int t = 0; t < 2; ++t) {
      int jb = w * 128 + t * 64;
      int jc = jb + lane;
      int row = jc >> 2, c8 = (jc & 3) << 3;
      gload16(A + (size_t)(m0 + row) * K + k0 + c8, sA + jb * 8);
      gload16(B + (size_t)(n0 + row) * K + k0 + c8, sB + jb * 8);
    }
    __syncthreads();
    bf16x8 af[4], bfr[4];
#pragma unroll
    for (int i = 0; i < 4; ++i) {
      af[i]  = *(const bf16x8*)(sA + (wr * 64 + i * 16 + l15) * 32 + g * 8);
      bfr[i] = *(const bf16x8*)(sB + (wc * 64 + i * 16 + l15) * 32 + g * 8);
    }
#pragma unroll
    for (int i = 0; i < 4; ++i)
#pragma unroll
      for (int j = 0; j < 4; ++j)
        acc[i][j] = mfma16(af[i], bfr[j], acc[i][j]);
  }
#pragma unroll
  for (int i = 0; i < 4; ++i)
#pragma unroll
    for (int j = 0; j < 4; ++j)
#pragma unroll
      for (int r = 0; r < 4; ++r) {
        int mm = m0 + wr * 64 + i * 16 + g * 4 + r;
        int nn = n0 + wc * 64 + j * 16 + l15;
        if (mode == 1)      ((float*)Cv)[(size_t)mm * N + nn] = acc[i][j][r];
        else if (mode == 0) ((u16*)Cv)[(size_t)mm * N + nn]   = f2b(acc[i][j][r]);
        else                ((u16*)Cv)[(size_t)nn * 2048 + (size_t)(mm >> 11) * 2097152 + (mm & 2047)]
                              = f2b(acc[i][j][r]);
      }
}

__global__ __launch_bounds__(256) void gemm_bf16out(const u16* __restrict__ A, const u16* __restrict__ B,
                                                    u16* __restrict__ C, int N, int K) {
  int bx, by; swz_bid(bx, by);
  gemm_body(A, B, C, N, K, by * 128, bx * 128, 0);
}
__global__ __launch_bounds__(256) void gemm_f32out(const u16* __restrict__ A, const u16* __restrict__ B,
                                                   float* __restrict__ C, int N, int K) {
  int bx, by; swz_bid(bx, by);
  gemm_body(A, B, C, N, K, by * 128, bx * 128, 1);
}
__global__ __launch_bounds__(256) void gemm_kv(const u16* __restrict__ A,
                                               const u16* __restrict__ Bk, const u16* __restrict__ Bv,
                                               u16* __restrict__ Ck, u16* __restrict__ Cv,
                                               int N, int K) {
  int bx, by; swz_bid(bx, by);
  bool isv = bx >= 8;
  gemm_body(A, isv ? Bv : Bk, isv ? Cv : Ck, N, K, by * 128, (bx & 7) * 128, isv ? 2 : 0);
}

// ---------------- RoPE (in place, bf16) — K only ----------------
__global__ __launch_bounds__(256) void rope_kernel(u16* __restrict__ t, const float* __restrict__ fc,
                                                   const float* __restrict__ fs, int nheads, int total) {
  int idx = blockIdx.x * 256 + threadIdx.x;
  if (idx >= total) return;
  int c = idx & 7;
  int tmp = idx >> 3;
  int h = tmp % nheads;
  int row = tmp / nheads;
  int s = row & (S_LEN - 1);
  int d0 = c << 3;
  u16* base = t + (size_t)row * (nheads * 128) + h * 128;
  u16x8 lo = *(const u16x8*)(base + d0);
  u16x8 hi = *(const u16x8*)(base + 64 + d0);
  const float* cp = fc + s * 64 + d0;
  const float* sp = fs + s * 64 + d0;
  u16x8 olo, ohi;
#pragma unroll
  for (int j = 0; j < 8; ++j) {
    float cv = cp[j], sn = sp[j];
    float a = b2f(lo[j]), b = b2f(hi[j]);
    olo[j] = f2b(a * cv - b * sn);
    ohi[j] = f2b(b * cv + a * sn);
  }
  *(u16x8*)(base + d0) = olo;
  *(u16x8*)(base + 64 + d0) = ohi;
}

// ---------------- causal GQA flash attention ----------------
// grid: (8, H, B); block 512 (8 waves x 16 q-rows). EQUAL-WORK PAIRED BLOCKS:
// each block processes q-panel qbA = 15-bx then qbB = bx (36 k-tiles total,
// constant across grid) -> 384 blocks, all resident (2/CU at 64 KB), no tail.
// Inner structure: swapped QK^T (lane owns q-row = lane&15), exp2 softmax,
// Q-RoPE fused, K/V^T double-buffered via global_load_lds w/ pre-swizzled
// sources, register-resident P via cvt_pk + shfl redistribution, defer-max.
__global__ __launch_bounds__(512) void attn_kernel(const u16* __restrict__ xq,
                                                   const u16* __restrict__ xk,
                                                   const u16* __restrict__ xvT,
                                                   const float* __restrict__ fc,
                                                   const float* __restrict__ fs,
                                                   u16* __restrict__ o) {
  __shared__ __align__(16) u16 smem[32768];     // 64 KB: K dbuf 32K + V^T dbuf 32K
  const int tid = threadIdx.x;
  const int w = tid >> 6, lane = tid & 63;
  const int l15 = lane & 15, g = lane >> 4;
  const int b = blockIdx.z, h = blockIdx.y;
  const int kvh = h / 3;
  const float sc2 = 0.08838834764831845f * 1.4426950408889634f;  // 1/sqrt(128)*log2e

  const u16* ksrc = xk + (size_t)b * 2097152 + kvh * 128;          // [s][1024]
  const u16* vsrc = xvT + (size_t)(b * 1024 + kvh * 128) * 2048;   // [d][2048]
  int koff[2], vofs[2], dst[2];
#pragma unroll
  for (int r = 0; r < 2; ++r) {
    int ck = r * 512 + tid;                    // K tile: 64 rows x 16 chunks
    int krow = ck >> 4, kj = (ck & 15) ^ (krow & 7);
    koff[r] = krow * 1024 + kj * 8;
    int cv = r * 512 + tid;                    // V^T tile: 128 rows x 8 chunks
    int vrow = cv >> 3, vj = (cv & 7) ^ (vrow & 7);
    vofs[r] = vrow * 2048 + vj * 8;
    dst[r] = (r * 512 + (tid & 448)) * 8;      // wave-uniform LDS chunk base
  }

  for (int panel = 0; panel < 2; ++panel) {
    const int qb = panel == 0 ? (15 - (int)blockIdx.x) : (int)blockIdx.x;
    const int q0 = qb * 128;
    const int qrow = q0 + w * 16 + l15;
    const u16* qptr = xq + (size_t)(b * S_LEN + qrow) * DM + h * 128;

    // Q load + fused RoPE + pre-scale
    bf16x8 qf[4];
#pragma unroll
    for (int dcp = 0; dcp < 2; ++dcp) {
      u16x8 Lo = *(const u16x8*)(qptr + dcp * 32 + g * 8);
      u16x8 Hi = *(const u16x8*)(qptr + 64 + dcp * 32 + g * 8);
      const float* cp = fc + qrow * 64 + dcp * 32 + g * 8;
      const float* sp = fs + qrow * 64 + dcp * 32 + g * 8;
      bf16x8 qlo, qhi;
#pragma unroll
      for (int j = 0; j < 8; ++j) {
        float cv = cp[j], sn = sp[j];
        float a = b2f(Lo[j]), bb = b2f(Hi[j]);
        qlo[j] = (__bf16)((a * cv - bb * sn) * sc2);
        qhi[j] = (__bf16)((bb * cv + a * sn) * sc2);
      }
      qf[dcp] = qlo;
      qf[dcp + 2] = qhi;
    }

    u16 *sKc = smem, *sKn = smem + 8192;
    u16 *sVc = smem + 16384, *sVn = smem + 24576;

    f32x4 accO[8];
#pragma unroll
    for (int i = 0; i < 8; ++i) accO[i] = 0.f;
    float m = -1e30f, lsum = 0.f;
    const int nt = 2 * qb + 2;

#pragma unroll
    for (int r = 0; r < 2; ++r) gload16(ksrc + koff[r], sKc + dst[r]);
#pragma unroll
    for (int r = 0; r < 2; ++r) gload16(vsrc + vofs[r], sVc + dst[r]);
    __syncthreads();

    for (int t = 0; t < nt; ++t) {
      if (t + 1 < nt) {
        int k0n = (t + 1) * 64;
#pragma unroll
        for (int r = 0; r < 2; ++r) gload16(ksrc + (size_t)k0n * 1024 + koff[r], sKn + dst[r]);
#pragma unroll
        for (int r = 0; r < 2; ++r) gload16(vsrc + k0n + vofs[r], sVn + dst[r]);
      }
      if (64 * t <= q0 + w * 16 + 15) {         // wave-level causal skip
        // S^T[k][q] = sum_d K[k][d] Q[q][d]
        f32x4 st[4];
        __builtin_amdgcn_s_setprio(1);
#pragma unroll
        for (int kt = 0; kt < 4; ++kt) {
          f32x4 a = 0.f;
          int row = kt * 16 + l15;
#pragma unroll
          for (int dc = 0; dc < 4; ++dc) {
            bf16x8 kf = *(const bf16x8*)(sKc + row * 128 + ((dc * 32 + g * 8) ^ ((row & 7) << 3)));
            a = mfma16(kf, qf[dc], a);
          }
          st[kt] = a;
        }
        __builtin_amdgcn_s_setprio(0);
        // causal mask (last two tiles only) + online softmax
        float sv[4][4];
        float pmax = -1e30f;
#pragma unroll
        for (int kt = 0; kt < 4; ++kt)
#pragma unroll
          for (int r = 0; r < 4; ++r) {
            float x = st[kt][r];
            if (t >= nt - 2) {
              int kk = t * 64 + kt * 16 + g * 4 + r;
              if (kk > qrow) x = -1e30f;
            }
            sv[kt][r] = x;
            pmax = fmaxf(pmax, x);
          }
        pmax = fmaxf(pmax, __shfl_xor(pmax, 16));
        pmax = fmaxf(pmax, __shfl_xor(pmax, 32));
        if (!__all(pmax - m <= 8.0f)) {        // defer-max
          float mnew = fmaxf(m, pmax);
          float corr = exp2f(m - mnew);
          lsum *= corr;
#pragma unroll
          for (int i = 0; i < 8; ++i) accO[i] *= corr;
          m = mnew;
        }
        // exp2 + pack P to bf16 pairs (register-resident)
        float ps = 0.f;
        u32 pk2[4][2];
#pragma unroll
        for (int kt = 0; kt < 4; ++kt) {
          float e0 = exp2f(sv[kt][0] - m);
          float e1 = exp2f(sv[kt][1] - m);
          float e2 = exp2f(sv[kt][2] - m);
          float e3 = exp2f(sv[kt][3] - m);
          ps += (e0 + e1) + (e2 + e3);
          pk2[kt][0] = cvtpk(e0, e1);
          pk2[kt][1] = cvtpk(e2, e3);
        }
        ps += __shfl_xor(ps, 16);
        ps += __shfl_xor(ps, 32);
        lsum += ps;
        // P redistribution: consumer (g,l15) frag ck needs P[k=ck*32+g*8+j][q=l15]
        bf16x8 pf[2];
        const int srcA = ((g & 1) << 5) + l15;
        const bool h2 = (g >> 1) != 0;
#pragma unroll
        for (int ck = 0; ck < 2; ++ck) {
          u32 a0 = __shfl(pk2[2 * ck][0], srcA, 64);
          u32 a1 = __shfl(pk2[2 * ck][1], srcA, 64);
          u32 a2 = __shfl(pk2[2 * ck][0], srcA + 16, 64);
          u32 a3 = __shfl(pk2[2 * ck][1], srcA + 16, 64);
          u32 b0 = __shfl(pk2[2 * ck + 1][0], srcA, 64);
          u32 b1 = __shfl(pk2[2 * ck + 1][1], srcA, 64);
          u32 b2 = __shfl(pk2[2 * ck + 1][0], srcA + 16, 64);
          u32 b3 = __shfl(pk2[2 * ck + 1][1], srcA + 16, 64);
          u32x4 fr;
          fr[0] = h2 ? b0 : a0;
          fr[1] = h2 ? b1 : a1;
          fr[2] = h2 ? b2 : a2;
          fr[3] = h2 ? b3 : a3;
          pf[ck] = __builtin_bit_cast(bf16x8, fr);
        }
        // PV: O^T[d][q] += V^T[d][k] * P[k][q]
        __builtin_amdgcn_s_setprio(1);
#pragma unroll
        for (int dt = 0; dt < 8; ++dt) {
          int row = dt * 16 + l15;
#pragma unroll
          for (int ck = 0; ck < 2; ++ck) {
            bf16x8 vf = *(const bf16x8*)(sVc + row * 64 + ((ck * 32 + g * 8) ^ ((row & 7) << 3)));
            accO[dt] = mfma16(vf, pf[ck], accO[dt]);
          }
        }
        __builtin_amdgcn_s_setprio(0);
      }
      __syncthreads();                          // drains stage vmcnt + cur reads done
      u16* tk = sKc; sKc = sKn; sKn = tk;
      u16* tv = sVc; sVc = sVn; sVn = tv;
    }
    // epilogue: normalize, transpose via wave-local LDS, coalesced writes
    u16* sO = smem + w * 2048;                  // per-wave [16][128], XOR-swizzled
    float invl = 1.0f / lsum;
#pragma unroll
    for (int dt = 0; dt < 8; ++dt)
#pragma unroll
      for (int r = 0; r < 4; ++r) {
        int d = dt * 16 + g * 4 + r;
        sO[(l15 * 128 + d) ^ ((l15 & 7) << 3)] = f2b(accO[dt][r] * invl);
      }
#pragma unroll
    for (int p = 0; p < 4; ++p) {
      int idx = p * 64 + lane;
      int q = idx >> 4, d0 = (idx & 15) << 3;
      u32x4 v = *(const u32x4*)(sO + ((q * 128 + d0) ^ ((q & 7) << 3)));
      *(u32x4*)(o + (size_t)(b * S_LEN + q0 + w * 16 + q) * DM + h * 128 + d0) = v;
    }
    __syncthreads();                            // epilogue LDS reads done before next panel restages
  }
}

// ---------------- launch ----------------
extern "C" void kernel_launch(void* const* d_in, const int* in_sizes, int n_in,
                              void* d_out, int out_size, void* d_ws, size_t ws_size,
                              hipStream_t stream) {
  const float* x  = (const float*)d_in[0];
  const float* fc = (const float*)d_in[1];
  const float* fs = (const float*)d_in[2];
  const float* wq = (const float*)d_in[4];
  const float* wk = (const float*)d_in[5];
  const float* wv = (const float*)d_in[6];
  const float* wo = (const float*)d_in[7];
  float* out = (float*)d_out;
  char* ws = (char*)d_ws;

  u16* xb  = (u16*)(ws);                 // x bf16      25,165,824
  u16* wqb = (u16*)(ws + 25165824);      // wq bf16     18,874,368
  u16* att = (u16*)(ws + 25165824);      // attn out (aliases wq/wk after death)
  u16* wkb = (u16*)(ws + 44040192);      // wk bf16      6,291,456
  u16* wvb = (u16*)(ws + 50331648);      // wv bf16      6,291,456
  u16* xqb = (u16*)(ws + 56623104);      // xq bf16     25,165,824
  u16* xkb = (u16*)(ws + 81788928);      // xk bf16      8,388,608
  u16* xvT = (u16*)(ws + 90177536);      // V^T bf16     8,388,608
  u16* wob = (u16*)(ws);                 // wo bf16 (aliases xb after death)

  cvt4_kernel<<<13824, 256, 0, stream>>>(x, xb, wq, wqb, wk, wkb, wv, wvb);

  gemm_bf16out<<<dim3(24, 32), 256, 0, stream>>>(xb, wqb, xqb, 3072, 3072);
  gemm_kv<<<dim3(16, 32), 256, 0, stream>>>(xb, wkb, wvb, xkb, xvT, 1024, 3072);

  cvt_kernel<<<4608, 256, 0, stream>>>(wo, wob, 1179648);   // after gemm_kv (aliases xb)
  rope_kernel<<<1024, 256, 0, stream>>>(xkb, fc, fs, NKV, 4096 * NKV * 8);  // K only

  attn_kernel<<<dim3(8, NH, 2), 512, 0, stream>>>(xqb, xkb, xvT, fc, fs, att);

  gemm_f32out<<<dim3(24, 32), 256, 0, stream>>>(att, wob, out, 3072, 3072);
}

// Round 7
// 440.835 us; speedup vs baseline: 1.3863x; 1.1320x over previous
//
#include <hip/hip_runtime.h>

typedef unsigned short u16;
typedef unsigned int u32;
typedef __attribute__((ext_vector_type(8))) __bf16 bf16x8;
typedef __attribute__((ext_vector_type(4))) float f32x4;
typedef __attribute__((ext_vector_type(4))) u32 u32x4;
typedef __attribute__((ext_vector_type(8))) u16 u16x8;
typedef __attribute__((ext_vector_type(4))) u16 u16x4;

#define S_LEN 2048
#define DM 3072
#define NH 24
#define NKV 8

__device__ __forceinline__ u16 f2b(float f) {
  u32 u = __builtin_bit_cast(u32, f);
  u = u + 0x7FFFu + ((u >> 16) & 1u);
  return (u16)(u >> 16);
}
__device__ __forceinline__ float b2f(u16 h) {
  u32 u = ((u32)h) << 16;
  return __builtin_bit_cast(float, u);
}
__device__ __forceinline__ u32 cvtpk(float lo, float hi) {
  u32 r;
  asm("v_cvt_pk_bf16_f32 %0, %1, %2" : "=v"(r) : "v"(lo), "v"(hi));
  return r;
}
__device__ __forceinline__ f32x4 mfma16(bf16x8 a, bf16x8 b, f32x4 c) {
  return __builtin_amdgcn_mfma_f32_16x16x32_bf16(a, b, c, 0, 0, 0);
}
__device__ __forceinline__ void gload16(const u16* g, u16* l) {
  __builtin_amdgcn_global_load_lds((const __attribute__((address_space(1))) void*)g,
                                   (__attribute__((address_space(3))) void*)l, 16, 0, 0);
}

// ---------------- f32 -> bf16 conversion ----------------
__device__ __forceinline__ void cvt_one(const float* __restrict__ s, u16* __restrict__ d, int j) {
  const f32x4* p = (const f32x4*)(s + (size_t)j * 8);
  f32x4 a = p[0], b = p[1];
  u16x8 o;
#pragma unroll
  for (int q = 0; q < 4; ++q) { o[q] = f2b(a[q]); o[q + 4] = f2b(b[q]); }
  *(u16x8*)(d + (size_t)j * 8) = o;
}
__global__ __launch_bounds__(256) void cvt_kernel(const float* __restrict__ s,
                                                  u16* __restrict__ d, int n8) {
  int i = blockIdx.x * 256 + threadIdx.x;
  if (i >= n8) return;
  cvt_one(s, d, i);
}
__global__ __launch_bounds__(256) void cvt4_kernel(const float* __restrict__ s0, u16* __restrict__ d0,
                                                   const float* __restrict__ s1, u16* __restrict__ d1,
                                                   const float* __restrict__ s2, u16* __restrict__ d2,
                                                   const float* __restrict__ s3, u16* __restrict__ d3) {
  int i = blockIdx.x * 256 + threadIdx.x;
  if (i < 1572864)      cvt_one(s0, d0, i);
  else if (i < 2752512) cvt_one(s1, d1, i - 1572864);
  else if (i < 3145728) cvt_one(s2, d2, i - 2752512);
  else                  cvt_one(s3, d3, i - 3145728);
}

// ---------------- XCD-aware block swizzle ----------------
__device__ __forceinline__ void swz_bid(int& bx, int& by) {
  int gx = gridDim.x;
  int tot = gx * gridDim.y;          // must be divisible by 8
  int id = blockIdx.y * gx + blockIdx.x;
  int cpx = tot >> 3;
  int s = (id & 7) * cpx + (id >> 3);
  bx = s % gx;
  by = s / gx;
}

// ---------------- 256-wide phase-interleaved GEMM ----------------
// C[m,n] = sum_k A[m,k]*B[n,k], both row-major over K (K = 3072, 48 K-tiles of 64).
// BM=256, BN=256 or 128, 512 threads = 8 waves (2M x 4N). Per-wave out 128 x BN/4.
// 4 phases/K-tile: P0{af0-3,bf kh0 | stage t+1 | 16*NJ/4 MFMA} P1{af4-7 kh0}
// P2{af+bf kh1} P3{af4-7 kh1 | vmcnt drain}. 2 barriers/phase. LDS chunk^(row&7)
// swizzle, pre-swizzled global sources. modes: 0 bf16, 1 f32, 2 V^T bf16.
template <int BN>
__device__ __forceinline__ void gemm256_body(const u16* __restrict__ A, const u16* __restrict__ B,
                                             void* __restrict__ Cv, int N, int K,
                                             int m0, int n0, int mode) {
  constexpr int NJ = BN / 64;                  // per-wave n-frags (4 or 2)
  constexpr int BHALF = BN / 128;              // B half-tiles (2 or 1)
  constexpr int BBUF = BN * 64;                // B u16 per buffer
  __shared__ __align__(16) u16 lds[32768 + 2 * BBUF];
  const int tid = threadIdx.x;
  const int lane = tid & 63;
  const int w = tid >> 6;
  const int l15 = lane & 15, g = lane >> 4;
  const int wm = w >> 2, wn = w & 3;
  const int srow = tid >> 3;                   // staging row 0..63
  const int scol = ((tid & 7) ^ (srow & 7)) * 8;   // pre-swizzled source col
  const u16* aS = A + (size_t)(m0 + srow) * K + scol;
  const u16* bS = B + (size_t)(n0 + srow) * K + scol;
  const int sdst = (tid & 448) * 8;            // wave-uniform LDS chunk base (u16)
  const int swz0 = (g ^ (l15 & 7)) * 8;        // kh0 swizzled chunk offset (u16)
  const int swz1 = ((4 + g) ^ (l15 & 7)) * 8;  // kh1
  const int aB0 = wm * 8192 + l15 * 64;
  const int bB0 = (BN == 256 ? ((wn >> 1) * 8192 + (wn & 1) * 4096) : wn * 2048) + l15 * 64;

  f32x4 acc[8][NJ];
#pragma unroll
  for (int i = 0; i < 8; ++i)
#pragma unroll
    for (int j = 0; j < NJ; ++j) acc[i][j] = 0.f;

  auto stage = [&](int k0, int bsel) {
#pragma unroll
    for (int h = 0; h < 2; ++h)
#pragma unroll
      for (int j = 0; j < 2; ++j)
        gload16(aS + (size_t)(h * 128 + j * 64) * K + k0,
                lds + bsel * 16384 + h * 8192 + j * 4096 + sdst);
#pragma unroll
    for (int h = 0; h < BHALF; ++h)
#pragma unroll
      for (int j = 0; j < 2; ++j)
        gload16(bS + (size_t)(h * 128 + j * 64) * K + k0,
                lds + 32768 + bsel * BBUF + h * 8192 + j * 4096 + sdst);
  };

  stage(0, 0);
  asm volatile("s_waitcnt vmcnt(0)" ::: "memory");
  __builtin_amdgcn_s_barrier();

  for (int t = 0; t < 48; ++t) {
    const int bsel = t & 1;
    const u16* ldsA = lds + bsel * 16384 + aB0;
    const u16* ldsB = lds + 32768 + bsel * BBUF + bB0;
    bf16x8 af[4], bf[NJ];
    // ---- P0: kh0, mi 0-3 (+ stage next tile)
#pragma unroll
    for (int i = 0; i < 4; ++i) af[i] = *(const bf16x8*)(ldsA + i * 1024 + swz0);
#pragma unroll
    for (int j = 0; j < NJ; ++j) bf[j] = *(const bf16x8*)(ldsB + j * 1024 + swz0);
    if (t < 47) stage((t + 1) * 64, bsel ^ 1);
    asm volatile("" ::: "memory");
    __builtin_amdgcn_s_barrier();
    asm volatile("s_waitcnt lgkmcnt(0)" ::: "memory");
    __builtin_amdgcn_sched_barrier(0);
    __builtin_amdgcn_s_setprio(1);
#pragma unroll
    for (int i = 0; i < 4; ++i)
#pragma unroll
      for (int j = 0; j < NJ; ++j) acc[i][j] = mfma16(af[i], bf[j], acc[i][j]);
    __builtin_amdgcn_s_setprio(0);
    asm volatile("" ::: "memory");
    __builtin_amdgcn_s_barrier();
    // ---- P1: kh0, mi 4-7 (bf reused)
#pragma unroll
    for (int i = 0; i < 4; ++i) af[i] = *(const bf16x8*)(ldsA + (4 + i) * 1024 + swz0);
    asm volatile("" ::: "memory");
    __builtin_amdgcn_s_barrier();
    asm volatile("s_waitcnt lgkmcnt(0)" ::: "memory");
    __builtin_amdgcn_sched_barrier(0);
    __builtin_amdgcn_s_setprio(1);
#pragma unroll
    for (int i = 0; i < 4; ++i)
#pragma unroll
      for (int j = 0; j < NJ; ++j) acc[4 + i][j] = mfma16(af[i], bf[j], acc[4 + i][j]);
    __builtin_amdgcn_s_setprio(0);
    asm volatile("" ::: "memory");
    __builtin_amdgcn_s_barrier();
    // ---- P2: kh1, mi 0-3
#pragma unroll
    for (int i = 0; i < 4; ++i) af[i] = *(const bf16x8*)(ldsA + i * 1024 + swz1);
#pragma unroll
    for (int j = 0; j < NJ; ++j) bf[j] = *(const bf16x8*)(ldsB + j * 1024 + swz1);
    asm volatile("" ::: "memory");
    __builtin_amdgcn_s_barrier();
    asm volatile("s_waitcnt lgkmcnt(0)" ::: "memory");
    __builtin_amdgcn_sched_barrier(0);
    __builtin_amdgcn_s_setprio(1);
#pragma unroll
    for (int i = 0; i < 4; ++i)
#pragma unroll
      for (int j = 0; j < NJ; ++j) acc[i][j] = mfma16(af[i], bf[j], acc[i][j]);
    __builtin_amdgcn_s_setprio(0);
    asm volatile("" ::: "memory");
    __builtin_amdgcn_s_barrier();
    // ---- P3: kh1, mi 4-7 (+ counted drain for next tile's buffer)
#pragma unroll
    for (int i = 0; i < 4; ++i) af[i] = *(const bf16x8*)(ldsA + (4 + i) * 1024 + swz1);
    asm volatile("" ::: "memory");
    asm volatile("s_waitcnt vmcnt(0)" ::: "memory");   // loads are ~3 phases old
    __builtin_amdgcn_s_barrier();
    asm volatile("s_waitcnt lgkmcnt(0)" ::: "memory");
    __builtin_amdgcn_sched_barrier(0);
    __builtin_amdgcn_s_setprio(1);
#pragma unroll
    for (int i = 0; i < 4; ++i)
#pragma unroll
      for (int j = 0; j < NJ; ++j) acc[4 + i][j] = mfma16(af[i], bf[j], acc[4 + i][j]);
    __builtin_amdgcn_s_setprio(0);
    asm volatile("" ::: "memory");
    __builtin_amdgcn_s_barrier();
  }
  // ---- epilogue
#pragma unroll
  for (int i = 0; i < 8; ++i)
#pragma unroll
    for (int j = 0; j < NJ; ++j) {
      int nn = n0 + wn * (BN / 4) + j * 16 + l15;
      int mmb = m0 + wm * 128 + i * 16 + g * 4;
      if (mode == 1) {
#pragma unroll
        for (int r = 0; r < 4; ++r)
          ((float*)Cv)[(size_t)(mmb + r) * N + nn] = acc[i][j][r];
      } else if (mode == 0) {
#pragma unroll
        for (int r = 0; r < 4; ++r)
          ((u16*)Cv)[(size_t)(mmb + r) * N + nn] = f2b(acc[i][j][r]);
      } else {
        u16x4 pk;
#pragma unroll
        for (int r = 0; r < 4; ++r) pk[r] = f2b(acc[i][j][r]);
        *(u16x4*)((u16*)Cv + (size_t)nn * 2048 + (size_t)(mmb >> 11) * 2097152 + (mmb & 2047)) = pk;
      }
    }
}

__global__ __launch_bounds__(512, 1) void gemm256_bf16(const u16* __restrict__ A, const u16* __restrict__ B,
                                                       u16* __restrict__ C, int N, int K) {
  int bx, by; swz_bid(bx, by);
  gemm256_body<256>(A, B, C, N, K, by * 256, bx * 256, 0);
}
__global__ __launch_bounds__(512, 1) void gemm256_f32(const u16* __restrict__ A, const u16* __restrict__ B,
                                                      float* __restrict__ C, int N, int K) {
  int bx, by; swz_bid(bx, by);
  gemm256_body<256>(A, B, C, N, K, by * 256, bx * 256, 1);
}
// K/V projections: grid (16,16); bx<8 -> K rows (row-major out), bx>=8 -> V (V^T out)
__global__ __launch_bounds__(512, 1) void gemm128_kv(const u16* __restrict__ A,
                                                     const u16* __restrict__ Bk, const u16* __restrict__ Bv,
                                                     u16* __restrict__ Ck, u16* __restrict__ Cv,
                                                     int K) {
  int bx, by; swz_bid(bx, by);
  bool isv = bx >= 8;
  gemm256_body<128>(A, isv ? Bv : Bk, isv ? Cv : Ck, 1024, K, by * 256, (bx & 7) * 128,
                    isv ? 2 : 0);
}

// ---------------- RoPE (in place, bf16) — K only ----------------
__global__ __launch_bounds__(256) void rope_kernel(u16* __restrict__ t, const float* __restrict__ fc,
                                                   const float* __restrict__ fs, int nheads, int total) {
  int idx = blockIdx.x * 256 + threadIdx.x;
  if (idx >= total) return;
  int c = idx & 7;
  int tmp = idx >> 3;
  int h = tmp % nheads;
  int row = tmp / nheads;
  int s = row & (S_LEN - 1);
  int d0 = c << 3;
  u16* base = t + (size_t)row * (nheads * 128) + h * 128;
  u16x8 lo = *(const u16x8*)(base + d0);
  u16x8 hi = *(const u16x8*)(base + 64 + d0);
  const float* cp = fc + s * 64 + d0;
  const float* sp = fs + s * 64 + d0;
  u16x8 olo, ohi;
#pragma unroll
  for (int j = 0; j < 8; ++j) {
    float cv = cp[j], sn = sp[j];
    float a = b2f(lo[j]), b = b2f(hi[j]);
    olo[j] = f2b(a * cv - b * sn);
    ohi[j] = f2b(b * cv + a * sn);
  }
  *(u16x8*)(base + d0) = olo;
  *(u16x8*)(base + 64 + d0) = ohi;
}

// ---------------- causal GQA flash attention (unchanged from r6) ----------------
__global__ __launch_bounds__(512) void attn_kernel(const u16* __restrict__ xq,
                                                   const u16* __restrict__ xk,
                                                   const u16* __restrict__ xvT,
                                                   const float* __restrict__ fc,
                                                   const float* __restrict__ fs,
                                                   u16* __restrict__ o) {
  __shared__ __align__(16) u16 smem[32768];     // 64 KB: K dbuf 32K + V^T dbuf 32K
  const int tid = threadIdx.x;
  const int w = tid >> 6, lane = tid & 63;
  const int l15 = lane & 15, g = lane >> 4;
  const int b = blockIdx.z, h = blockIdx.y;
  const int kvh = h / 3;
  const float sc2 = 0.08838834764831845f * 1.4426950408889634f;  // 1/sqrt(128)*log2e

  const u16* ksrc = xk + (size_t)b * 2097152 + kvh * 128;          // [s][1024]
  const u16* vsrc = xvT + (size_t)(b * 1024 + kvh * 128) * 2048;   // [d][2048]
  int koff[2], vofs[2], dst[2];
#pragma unroll
  for (int r = 0; r < 2; ++r) {
    int ck = r * 512 + tid;                    // K tile: 64 rows x 16 chunks
    int krow = ck >> 4, kj = (ck & 15) ^ (krow & 7);
    koff[r] = krow * 1024 + kj * 8;
    int cv = r * 512 + tid;                    // V^T tile: 128 rows x 8 chunks
    int vrow = cv >> 3, vj = (cv & 7) ^ (vrow & 7);
    vofs[r] = vrow * 2048 + vj * 8;
    dst[r] = (r * 512 + (tid & 448)) * 8;      // wave-uniform LDS chunk base
  }

  for (int panel = 0; panel < 2; ++panel) {
    const int qb = panel == 0 ? (15 - (int)blockIdx.x) : (int)blockIdx.x;
    const int q0 = qb * 128;
    const int qrow = q0 + w * 16 + l15;
    const u16* qptr = xq + (size_t)(b * S_LEN + qrow) * DM + h * 128;

    bf16x8 qf[4];
#pragma unroll
    for (int dcp = 0; dcp < 2; ++dcp) {
      u16x8 Lo = *(const u16x8*)(qptr + dcp * 32 + g * 8);
      u16x8 Hi = *(const u16x8*)(qptr + 64 + dcp * 32 + g * 8);
      const float* cp = fc + qrow * 64 + dcp * 32 + g * 8;
      const float* sp = fs + qrow * 64 + dcp * 32 + g * 8;
      bf16x8 qlo, qhi;
#pragma unroll
      for (int j = 0; j < 8; ++j) {
        float cv = cp[j], sn = sp[j];
        float a = b2f(Lo[j]), bb = b2f(Hi[j]);
        qlo[j] = (__bf16)((a * cv - bb * sn) * sc2);
        qhi[j] = (__bf16)((bb * cv + a * sn) * sc2);
      }
      qf[dcp] = qlo;
      qf[dcp + 2] = qhi;
    }

    u16 *sKc = smem, *sKn = smem + 8192;
    u16 *sVc = smem + 16384, *sVn = smem + 24576;

    f32x4 accO[8];
#pragma unroll
    for (int i = 0; i < 8; ++i) accO[i] = 0.f;
    float m = -1e30f, lsum = 0.f;
    const int nt = 2 * qb + 2;

#pragma unroll
    for (int r = 0; r < 2; ++r) gload16(ksrc + koff[r], sKc + dst[r]);
#pragma unroll
    for (int r = 0; r < 2; ++r) gload16(vsrc + vofs[r], sVc + dst[r]);
    __syncthreads();

    for (int t = 0; t < nt; ++t) {
      if (t + 1 < nt) {
        int k0n = (t + 1) * 64;
#pragma unroll
        for (int r = 0; r < 2; ++r) gload16(ksrc + (size_t)k0n * 1024 + koff[r], sKn + dst[r]);
#pragma unroll
        for (int r = 0; r < 2; ++r) gload16(vsrc + k0n + vofs[r], sVn + dst[r]);
      }
      if (64 * t <= q0 + w * 16 + 15) {         // wave-level causal skip
        f32x4 st[4];
        __builtin_amdgcn_s_setprio(1);
#pragma unroll
        for (int kt = 0; kt < 4; ++kt) {
          f32x4 a = 0.f;
          int row = kt * 16 + l15;
#pragma unroll
          for (int dc = 0; dc < 4; ++dc) {
            bf16x8 kf = *(const bf16x8*)(sKc + row * 128 + ((dc * 32 + g * 8) ^ ((row & 7) << 3)));
            a = mfma16(kf, qf[dc], a);
          }
          st[kt] = a;
        }
        __builtin_amdgcn_s_setprio(0);
        float sv[4][4];
        float pmax = -1e30f;
#pragma unroll
        for (int kt = 0; kt < 4; ++kt)
#pragma unroll
          for (int r = 0; r < 4; ++r) {
            float x = st[kt][r];
            if (t >= nt - 2) {
              int kk = t * 64 + kt * 16 + g * 4 + r;
              if (kk > qrow) x = -1e30f;
            }
            sv[kt][r] = x;
            pmax = fmaxf(pmax, x);
          }
        pmax = fmaxf(pmax, __shfl_xor(pmax, 16));
        pmax = fmaxf(pmax, __shfl_xor(pmax, 32));
        if (!__all(pmax - m <= 8.0f)) {        // defer-max
          float mnew = fmaxf(m, pmax);
          float corr = exp2f(m - mnew);
          lsum *= corr;
#pragma unroll
          for (int i = 0; i < 8; ++i) accO[i] *= corr;
          m = mnew;
        }
        float ps = 0.f;
        u32 pk2[4][2];
#pragma unroll
        for (int kt = 0; kt < 4; ++kt) {
          float e0 = exp2f(sv[kt][0] - m);
          float e1 = exp2f(sv[kt][1] - m);
          float e2 = exp2f(sv[kt][2] - m);
          float e3 = exp2f(sv[kt][3] - m);
          ps += (e0 + e1) + (e2 + e3);
          pk2[kt][0] = cvtpk(e0, e1);
          pk2[kt][1] = cvtpk(e2, e3);
        }
        ps += __shfl_xor(ps, 16);
        ps += __shfl_xor(ps, 32);
        lsum += ps;
        bf16x8 pf[2];
        const int srcA = ((g & 1) << 5) + l15;
        const bool h2 = (g >> 1) != 0;
#pragma unroll
        for (int ck = 0; ck < 2; ++ck) {
          u32 a0 = __shfl(pk2[2 * ck][0], srcA, 64);
          u32 a1 = __shfl(pk2[2 * ck][1], srcA, 64);
          u32 a2 = __shfl(pk2[2 * ck][0], srcA + 16, 64);
          u32 a3 = __shfl(pk2[2 * ck][1], srcA + 16, 64);
          u32 b0 = __shfl(pk2[2 * ck + 1][0], srcA, 64);
          u32 b1 = __shfl(pk2[2 * ck + 1][1], srcA, 64);
          u32 b2 = __shfl(pk2[2 * ck + 1][0], srcA + 16, 64);
          u32 b3 = __shfl(pk2[2 * ck + 1][1], srcA + 16, 64);
          u32x4 fr;
          fr[0] = h2 ? b0 : a0;
          fr[1] = h2 ? b1 : a1;
          fr[2] = h2 ? b2 : a2;
          fr[3] = h2 ? b3 : a3;
          pf[ck] = __builtin_bit_cast(bf16x8, fr);
        }
        __builtin_amdgcn_s_setprio(1);
#pragma unroll
        for (int dt = 0; dt < 8; ++dt) {
          int row = dt * 16 + l15;
#pragma unroll
          for (int ck = 0; ck < 2; ++ck) {
            bf16x8 vf = *(const bf16x8*)(sVc + row * 64 + ((ck * 32 + g * 8) ^ ((row & 7) << 3)));
            accO[dt] = mfma16(vf, pf[ck], accO[dt]);
          }
        }
        __builtin_amdgcn_s_setprio(0);
      }
      __syncthreads();
      u16* tk = sKc; sKc = sKn; sKn = tk;
      u16* tv = sVc; sVc = sVn; sVn = tv;
    }
    u16* sO = smem + w * 2048;
    float invl = 1.0f / lsum;
#pragma unroll
    for (int dt = 0; dt < 8; ++dt)
#pragma unroll
      for (int r = 0; r < 4; ++r) {
        int d = dt * 16 + g * 4 + r;
        sO[(l15 * 128 + d) ^ ((l15 & 7) << 3)] = f2b(accO[dt][r] * invl);
      }
#pragma unroll
    for (int p = 0; p < 4; ++p) {
      int idx = p * 64 + lane;
      int q = idx >> 4, d0 = (idx & 15) << 3;
      u32x4 v = *(const u32x4*)(sO + ((q * 128 + d0) ^ ((q & 7) << 3)));
      *(u32x4*)(o + (size_t)(b * S_LEN + q0 + w * 16 + q) * DM + h * 128 + d0) = v;
    }
    __syncthreads();
  }
}

// ---------------- launch ----------------
extern "C" void kernel_launch(void* const* d_in, const int* in_sizes, int n_in,
                              void* d_out, int out_size, void* d_ws, size_t ws_size,
                              hipStream_t stream) {
  const float* x  = (const float*)d_in[0];
  const float* fc = (const float*)d_in[1];
  const float* fs = (const float*)d_in[2];
  const float* wq = (const float*)d_in[4];
  const float* wk = (const float*)d_in[5];
  const float* wv = (const float*)d_in[6];
  const float* wo = (const float*)d_in[7];
  float* out = (float*)d_out;
  char* ws = (char*)d_ws;

  u16* xb  = (u16*)(ws);                 // x bf16      25,165,824
  u16* wqb = (u16*)(ws + 25165824);      // wq bf16     18,874,368
  u16* att = (u16*)(ws + 25165824);      // attn out (aliases wq/wk after death)
  u16* wkb = (u16*)(ws + 44040192);      // wk bf16      6,291,456
  u16* wvb = (u16*)(ws + 50331648);      // wv bf16      6,291,456
  u16* xqb = (u16*)(ws + 56623104);      // xq bf16     25,165,824
  u16* xkb = (u16*)(ws + 81788928);      // xk bf16      8,388,608
  u16* xvT = (u16*)(ws + 90177536);      // V^T bf16     8,388,608
  u16* wob = (u16*)(ws);                 // wo bf16 (aliases xb after death)

  cvt4_kernel<<<13824, 256, 0, stream>>>(x, xb, wq, wqb, wk, wkb, wv, wvb);

  gemm256_bf16<<<dim3(12, 16), 512, 0, stream>>>(xb, wqb, xqb, 3072, 3072);
  gemm128_kv<<<dim3(16, 16), 512, 0, stream>>>(xb, wkb, wvb, xkb, xvT, 3072);

  cvt_kernel<<<4608, 256, 0, stream>>>(wo, wob, 1179648);   // after gemm_kv (aliases xb)
  rope_kernel<<<1024, 256, 0, stream>>>(xkb, fc, fs, NKV, 4096 * NKV * 8);  // K only

  attn_kernel<<<dim3(8, NH, 2), 512, 0, stream>>>(xqb, xkb, xvT, fc, fs, att);

  gemm256_f32<<<dim3(12, 16), 512, 0, stream>>>(att, wob, out, 3072, 3072);
}